// Round 18
// baseline (43.875 us; speedup 1.0000x reference)
//
#include <hip/hip_runtime.h>

#define DTF (1.0f/120.0f)

constexpr int Bn = 2048, Tn = 2048, NS = Tn - 1, ZF = Tn * 3;
constexpr int BT = 256;               // 4 waves x 64 lanes
constexpr int NCG = 8;                // chunk groups: block covers chunks 4cg..4cg+3 (L=64)
constexpr int NBG = Bn / 64;          // 32 trajectory groups
constexpr int NBLK = NBG * NCG;       // 256 blocks = 1 per CU
constexpr int TSTR = 97;              // LDS tile row stride (conflict-free both phases)
constexpr int SEGF = 64 * TSTR;       // floats per buffer

// ---- main: block-local staged z (32 zi-rows per segment), staggered wave windows ----
__global__ __launch_bounds__(BT, 1) void ekf_main(const float* __restrict__ params,
                                                  const float* __restrict__ meas,
                                                  double* __restrict__ part)
{
    __shared__ float tile[2 * SEGF];          // 49.7 KB double buffer
    __shared__ double wsum[4];

    const int tid = threadIdx.x, w = tid >> 6, lane = tid & 63;
    const int bg = blockIdx.x & 31, cg = blockIdx.x >> 5;
    const int c = 4 * cg + w;                 // this wave's chunk
    const float dt = DTF, fric = params[0], damping = params[1];
    const float a = 1.f - dt * damping, dfr = dt * fric;
    const float dt2 = dt * dt, a2 = a * a;
    const float qp = 2e-10f, qv = 3e-7f, qth = 1e-2f, qdth = 1e-1f;
    const float Rp = 2.5e-7f, Rt = 9.1e-3f;
    const float* __restrict__ zb = meas + (size_t)bg * 64 * ZF;

    const int Z0 = (cg == 0) ? 0 : 64 * (4 * cg - 1);  // block zi window start
    const int nseg = (cg == 0) ? 9 : 11;               // 32-zi segments
    const int jw = 64 * max(c - 1, 0);                 // wave start step
    const int j0own = 64 * c;                          // owned [j0own, jend)
    const int jend = min(64 * c + 64, NS);
    const bool head = (c <= 1);                        // exact path (jw == 0)

#define LOADSEG(Rx, S) do { \
    int zs_ = Z0 + 32 * (S); \
    _Pragma("unroll") \
    for (int k_ = 0; k_ < 24; ++k_) { \
        int f_ = tid + 256 * k_; \
        int r_ = f_ / 96, col_ = f_ - 96 * r_; \
        int gi_ = min(3 * zs_ + col_, ZF - 1); \
        Rx[k_] = zb[(size_t)r_ * ZF + gi_]; \
    } } while (0)

#define WRITESEG(Rx, BUF) do { \
    float* tb_ = &tile[(BUF) * SEGF]; \
    _Pragma("unroll") \
    for (int k_ = 0; k_ < 24; ++k_) { \
        int f_ = tid + 256 * k_; \
        int r_ = f_ / 96, col_ = f_ - 96 * r_; \
        tb_[r_ * TSTR + col_] = Rx[k_]; \
    } } while (0)

    float R0[24], R1[24];
    LOADSEG(R0, 0);
    LOADSEG(R1, 1);

    // converged gains (warm waves), computed under the in-flight loads
    float ckx0, ckx1, ckt0, ckt1, cisx, cist, cdet;
    {
        float x00 = 0.01f, x01 = 0.f, x11 = 0.01f, t00 = 0.01f, t01 = 0.f, t11 = 0.01f;
        for (int t = 0; t < 48; ++t) {
            float Pp00 = fmaf(dt2, x11, fmaf(2.f * dt, x01, x00)) + qp;
            float Pp01 = a * fmaf(dt, x11, x01);
            float Pp11 = fmaf(a2, x11, qv);
            float Sx = Pp00 + Rp, isx = __builtin_amdgcn_rcpf(Sx);
            float kx0 = Pp00 * isx, kx1 = Pp01 * isx;
            x00 = Pp00 - kx0 * Pp00; x01 = Pp01 - kx0 * Pp01; x11 = Pp11 - kx1 * Pp01;
            float Tp00 = fmaf(dt2, t11, fmaf(2.f * dt, t01, t00)) + qth;
            float Tp01 = fmaf(dt, t11, t01);
            float Tp11 = t11 + qdth;
            float St = Tp00 + Rt, ist = __builtin_amdgcn_rcpf(St);
            float kt0 = Tp00 * ist, kt1 = Tp01 * ist;
            t00 = Tp00 - kt0 * Tp00; t01 = Tp01 - kt0 * Tp01; t11 = Tp11 - kt1 * Tp01;
            ckx0 = kx0; ckx1 = kx1; ckt0 = kt0; ckt1 = kt1;
            cisx = isx; cist = ist; cdet = Sx * Sx * St;
        }
    }

    WRITESEG(R0, 0);                           // waits R0 loads (reg dep)
    __syncthreads();                           // buf0 visible

    float s0 = 0.f, s1 = 0.f, s2 = 0.f, s3 = 0.f, s4 = 0.f, s5 = 0.f;
    float hx00 = 0.01f, hx01 = 0.f, hx11 = 0.01f;   // head per-step Riccati state
    float ht00 = 0.01f, ht01 = 0.f, ht11 = 0.01f;
    float facc = 0.f;

    for (int s = 0; s < nseg; ++s) {
        // stage seg s+1 into the other buffer; issue seg s+2 loads into freed regs
        if (s + 1 < nseg) { if (((s + 1) & 1) == 1) WRITESEG(R1, 1); else WRITESEG(R0, 0); }
        if (s + 2 < nseg) { if ((s & 1) == 0) LOADSEG(R0, s + 2); else LOADSEG(R1, s + 2); }

        // consume seg s
        const int zs = Z0 + 32 * s;
        const float* tb = &tile[(s & 1) * SEGF + lane * TSTR];
        if (jw >= zs && jw < zs + 32) {        // FD init (z[jw], z[jw+1] same segment)
            int d0 = 3 * (jw - zs);
            float z0 = tb[d0], z1 = tb[d0+1], z2 = tb[d0+2];
            float z3 = tb[d0+3], z4 = tb[d0+4], z5 = tb[d0+5];
            s0 = z0; s1 = z1; s4 = z2;
            s2 = (z3 - z0) / dt; s3 = (z4 - z1) / dt; s5 = (z5 - z2) / dt;
        }
        const int jA = max(jw, zs - 1), jB = min(jend, zs + 31);
        if (head) {
            #pragma unroll 4
            for (int j = jA; j < jB; ++j) {
                int d = 3 * (j + 1 - zs);
                float z0 = tb[d], z1 = tb[d+1], z2 = tb[d+2];
                float Pp00 = fmaf(dt2, hx11, fmaf(2.f*dt, hx01, hx00)) + qp;
                float Pp01 = a * fmaf(dt, hx11, hx01);
                float Pp11 = fmaf(a2, hx11, qv);
                float Sx = Pp00 + Rp, isx = __builtin_amdgcn_rcpf(Sx);
                float kx0 = Pp00 * isx, kx1 = Pp01 * isx;
                hx00 = Pp00 - kx0*Pp00; hx01 = Pp01 - kx0*Pp01; hx11 = Pp11 - kx1*Pp01;
                float Tp00 = fmaf(dt2, ht11, fmaf(2.f*dt, ht01, ht00)) + qth;
                float Tp01 = fmaf(dt, ht11, ht01);
                float Tp11 = ht11 + qdth;
                float St = Tp00 + Rt, ist = __builtin_amdgcn_rcpf(St);
                float kt0 = Tp00 * ist, kt1 = Tp01 * ist;
                ht00 = Tp00 - kt0*Tp00; ht01 = Tp01 - kt0*Tp01; ht11 = Tp11 - kt1*Tp01;
                float p0 = fmaf(dt, s2, s0), p1 = fmaf(dt, s3, s1), p4 = fmaf(dt, s5, s4);
                float p2 = fmaf(a, s2, -copysignf(dfr, s2));
                float p3 = fmaf(a, s3, -copysignf(dfr, s3));
                float y0 = z0 - p0, y1 = z1 - p1, y2 = z2 - p4;
                s0 = fmaf(kx0, y0, p0); s1 = fmaf(kx0, y1, p1);
                s2 = fmaf(kx1, y0, p2); s3 = fmaf(kx1, y1, p3);
                s4 = fmaf(kt0, y2, p4); s5 = fmaf(kt1, y2, s5);
                if (j >= j0own)
                    facc += Sx*Sx*St + isx * fmaf(y0, y0, y1*y1) + ist * y2*y2;
            }
        } else {
            #pragma unroll 4
            for (int j = jA; j < jB; ++j) {
                int d = 3 * (j + 1 - zs);
                float z0 = tb[d], z1 = tb[d+1], z2 = tb[d+2];
                float p0 = fmaf(dt, s2, s0), p1 = fmaf(dt, s3, s1), p4 = fmaf(dt, s5, s4);
                float p2 = fmaf(a, s2, -copysignf(dfr, s2));
                float p3 = fmaf(a, s3, -copysignf(dfr, s3));
                float y0 = z0 - p0, y1 = z1 - p1, y2 = z2 - p4;
                s0 = fmaf(ckx0, y0, p0); s1 = fmaf(ckx0, y1, p1);
                s2 = fmaf(ckx1, y0, p2); s3 = fmaf(ckx1, y1, p3);
                s4 = fmaf(ckt0, y2, p4); s5 = fmaf(ckt1, y2, s5);
                if (j >= j0own)
                    facc += cdet + cisx * fmaf(y0, y0, y1*y1) + cist * y2*y2;
            }
        }
        __syncthreads();                       // reads of buf[s&1] done; next write safe
    }
#undef WRITESEG
#undef LOADSEG

    // per-wave reduce -> block partial (plain store, no atomics)
    double acc = (double)facc;
    for (int off = 32; off; off >>= 1) acc += __shfl_down(acc, off);
    if (lane == 0) wsum[w] = acc;
    __syncthreads();
    if (tid == 0) part[blockIdx.x] = wsum[0] + wsum[1] + wsum[2] + wsum[3];
}

// ---- finalize: reduce 256 partials ----
__global__ void finalize_kernel(const double* __restrict__ part, float* __restrict__ out)
{
    const int tid = threadIdx.x;               // 256 threads
    double v = part[tid];
    for (int off = 32; off; off >>= 1) v += __shfl_down(v, off);
    __shared__ double wp[4];
    if ((tid & 63) == 0) wp[tid >> 6] = v;
    __syncthreads();
    if (tid == 0) {
        double t = wp[0] + wp[1] + wp[2] + wp[3];
        out[0] = (float)(t / ((double)Bn * (double)NS));
    }
}

extern "C" void kernel_launch(void* const* d_in, const int* in_sizes, int n_in,
                              void* d_out, int out_size, void* d_ws, size_t ws_size,
                              hipStream_t stream)
{
    const float* params = (const float*)d_in[0];
    const float* meas = (const float*)d_in[1];
    double* part = (double*)d_ws;
    float* out = (float*)d_out;

    hipLaunchKernelGGL(ekf_main, dim3(NBLK), dim3(BT), 0, stream, params, meas, part);
    hipLaunchKernelGGL(finalize_kernel, dim3(1), dim3(256), 0, stream, part, out);
}

// Round 19
// 42.921 us; speedup vs baseline: 1.0222x; 1.0222x over previous
//
#include <hip/hip_runtime.h>

#define DTF (1.0f/120.0f)

constexpr int Bn = 2048, Tn = 2048, NS = Tn - 1, ZF = Tn * 3;
constexpr int BT = 128;               // 2 waves = 1 trajectory; 128 chunks of L=16
constexpr int NBLK = Bn;              // 2048 blocks
constexpr int GRAN = ZF / 4;          // 1536 16B-granules per trajectory
constexpr int RROWS = 80;             // gain rows = local span (64 warm + 16 owned)

// ws: [0,2560) gain table (80 x 8 floats); [4096,...) 2048 doubles partials
constexpr int WS_PART = 4096;

// LDS-side-only swizzle: granule g -> byte offset (keeps 16B alignment)
__device__ __forceinline__ int ldsb(int g) { return (g << 4) ^ (((g >> 5) & 3) << 4); }

// ---- gains: serial 2x2 Riccati from P0, 80 rows {kx0,kx1,kt0,kt1,isx,ist,det,0} ----
__global__ void gains_kernel(const float* __restrict__ params, float* __restrict__ gt)
{
    if (threadIdx.x != 0) return;
    const float dt = DTF;
    const float damping = params[1];
    const float a = 1.f - dt * damping;
    const float dt2 = dt * dt, a2 = a * a;
    const float qp = 2e-10f, qv = 3e-7f, qth = 1e-2f, qdth = 1e-1f;
    const float Rp = 2.5e-7f, Rt = 9.1e-3f;
    float x00 = 0.01f, x01 = 0.f, x11 = 0.01f;
    float t00 = 0.01f, t01 = 0.f, t11 = 0.01f;
    for (int t = 0; t < RROWS; ++t) {
        float Pp00 = fmaf(dt2, x11, fmaf(2.f * dt, x01, x00)) + qp;
        float Pp01 = a * fmaf(dt, x11, x01);
        float Pp11 = fmaf(a2, x11, qv);
        float Sx = Pp00 + Rp, isx = __builtin_amdgcn_rcpf(Sx);
        float kx0 = Pp00 * isx, kx1 = Pp01 * isx;
        x00 = Pp00 - kx0 * Pp00; x01 = Pp01 - kx0 * Pp01; x11 = Pp11 - kx1 * Pp01;
        float Tp00 = fmaf(dt2, t11, fmaf(2.f * dt, t01, t00)) + qth;
        float Tp01 = fmaf(dt, t11, t01);
        float Tp11 = t11 + qdth;
        float St = Tp00 + Rt, ist = __builtin_amdgcn_rcpf(St);
        float kt0 = Tp00 * ist, kt1 = Tp01 * ist;
        t00 = Tp00 - kt0 * Tp00; t01 = Tp01 - kt0 * Tp01; t11 = Tp11 - kt1 * Tp01;
        float* row = gt + (size_t)t * 8;
        row[0] = kx0; row[1] = kx1; row[2] = kt0; row[3] = kt1;
        row[4] = isx; row[5] = ist; row[6] = Sx * Sx * St; row[7] = 0.f;
    }
}

// ---- main: 2 waves per trajectory; all-LDS inner loop (z + gains), no global in loop ----
__global__ __launch_bounds__(BT, 4) void ekf_main(const float* __restrict__ params,
                                                  const float* __restrict__ meas,
                                                  const float* __restrict__ gt,
                                                  double* __restrict__ part)
{
    __shared__ __align__(16) float lds[GRAN * 4];   // 24 KB: whole trajectory (swizzled)
    __shared__ __align__(16) float gtab[RROWS * 8]; // 2.56 KB gain table
    __shared__ double wsum[2];

    const int tid = threadIdx.x;                    // chunk index c
    const int B = blockIdx.x;                       // trajectory
    const float dt = DTF;
    const float fric = params[0];
    const float damping = params[1];
    const float a = 1.f - dt * damping;
    const float dfr = dt * fric;
    const char* __restrict__ zb = (const char*)meas + (size_t)B * (ZF * 4);
    char* __restrict__ ldsc = (char*)lds;

    // coalesced stage: lane-linear global loads (full 128B lines), swizzled LDS writes
    float4 st[12];
    #pragma unroll
    for (int i = 0; i < 12; ++i)
        st[i] = *(const float4*)(zb + (size_t)(128 * i + tid) * 16);
    // gain table -> LDS (640 floats, coalesced)
    float gs[5];
    #pragma unroll
    for (int i = 0; i < 5; ++i) gs[i] = gt[128 * i + tid];

    #pragma unroll
    for (int i = 0; i < 12; ++i) {
        int g = 128 * i + tid;
        *(float4*)(ldsc + ldsb(g)) = st[i];
    }
    #pragma unroll
    for (int i = 0; i < 5; ++i) gtab[128 * i + tid] = gs[i];
    __syncthreads();                                // staging visible to both waves

    // per-lane geometry: c<=4 exact from t=0; else jw = 16c-64 (W=64)
    const int c = tid;
    const int jw = (c <= 4) ? 0 : (16 * c - 64);
    const int gB = (3 * jw) >> 2;                   // 16B-aligned (jw % 4 == 0)
    const int ro0 = 16 * c - jw;                    // owned local window [ro0, ro1)
    const int ro1 = min(16 * c + 16, NS) - jw;

    // FD init at jw (c<=4: exact reference init)
    float s0, s1, s2, s3, s4, s5;
    {
        float4 u0 = *(const float4*)(ldsc + ldsb(gB));
        float4 u1 = *(const float4*)(ldsc + ldsb(gB + 1));
        s0 = u0.x; s1 = u0.y; s4 = u0.z;
        s2 = (u0.w - u0.x) / dt; s3 = (u1.x - u0.y) / dt; s5 = (u1.y - u0.z) / dt;
    }

    float facc = 0.f;
    const float4* __restrict__ gl = (const float4*)gtab;

#define ZREAD(M) \
    float4 v0 = *(const float4*)(ldsc + ldsb(min(gB + 3*(M),     GRAN-1))); \
    float4 v1 = *(const float4*)(ldsc + ldsb(min(gB + 3*(M) + 1, GRAN-1))); \
    float4 v2 = *(const float4*)(ldsc + ldsb(min(gB + 3*(M) + 2, GRAN-1))); \
    float4 v3 = *(const float4*)(ldsc + ldsb(min(gB + 3*(M) + 3, GRAN-1))); \
    float zv[12] = { v0.w, v1.x, v1.y, v1.z, v1.w, v2.x, \
                     v2.y, v2.z, v2.w, v3.x, v3.y, v3.z };

#define STEP(SS, GA, GB_) { \
    float p0 = fmaf(dt, s2, s0), p1 = fmaf(dt, s3, s1), p4 = fmaf(dt, s5, s4); \
    float p2 = fmaf(a, s2, -copysignf(dfr, s2)); \
    float p3 = fmaf(a, s3, -copysignf(dfr, s3)); \
    float y0 = zv[3*(SS)] - p0, y1 = zv[3*(SS)+1] - p1, y2 = zv[3*(SS)+2] - p4; \
    s0 = fmaf(GA.x, y0, p0); s1 = fmaf(GA.x, y1, p1); \
    s2 = fmaf(GA.y, y0, p2); s3 = fmaf(GA.y, y1, p3); \
    s4 = fmaf(GA.z, y2, p4); s5 = fmaf(GA.w, y2, s5); \
    int r = 4 * m + (SS); \
    if (r >= ro0 && r < ro1) \
        facc += GB_.z + GB_.x * fmaf(y0, y0, y1 * y1) + GB_.y * y2 * y2; }

    // 20 batches of 4 steps; z + gains all from LDS (broadcast reads for gains)
    #pragma unroll 2
    for (int m = 0; m < 20; ++m) {
        float4 G0 = gl[8*m+0], G1 = gl[8*m+1], G2 = gl[8*m+2], G3 = gl[8*m+3];
        float4 G4 = gl[8*m+4], G5 = gl[8*m+5], G6 = gl[8*m+6], G7 = gl[8*m+7];
        ZREAD(m)
        STEP(0, G0, G1) STEP(1, G2, G3) STEP(2, G4, G5) STEP(3, G6, G7)
    }
#undef STEP
#undef ZREAD

    // per-wave reduce, then block sum (covers all 128 chunks = whole trajectory)
    double acc = (double)facc;
    for (int off = 32; off; off >>= 1) acc += __shfl_down(acc, off);
    if ((tid & 63) == 0) wsum[tid >> 6] = acc;
    __syncthreads();
    if (tid == 0) part[B] = wsum[0] + wsum[1];
}

// ---- finalize: reduce 2048 partials ----
__global__ void finalize_kernel(const double* __restrict__ part, float* __restrict__ out)
{
    const int tid = threadIdx.x;               // 1024 threads
    double v = part[tid] + part[tid + 1024];
    for (int off = 32; off; off >>= 1) v += __shfl_down(v, off);
    __shared__ double wp[16];
    if ((tid & 63) == 0) wp[tid >> 6] = v;
    __syncthreads();
    if (tid == 0) {
        double t = 0.0;
        #pragma unroll
        for (int i = 0; i < 16; ++i) t += wp[i];
        out[0] = (float)(t / ((double)Bn * (double)NS));
    }
}

extern "C" void kernel_launch(void* const* d_in, const int* in_sizes, int n_in,
                              void* d_out, int out_size, void* d_ws, size_t ws_size,
                              hipStream_t stream)
{
    const float* params = (const float*)d_in[0];
    const float* meas = (const float*)d_in[1];
    float* gt = (float*)d_ws;
    double* part = (double*)((char*)d_ws + WS_PART);
    float* out = (float*)d_out;

    hipLaunchKernelGGL(gains_kernel, dim3(1), dim3(64), 0, stream, params, gt);
    hipLaunchKernelGGL(ekf_main, dim3(NBLK), dim3(BT), 0, stream, params, meas, gt, part);
    hipLaunchKernelGGL(finalize_kernel, dim3(1), dim3(1024), 0, stream, part, out);
}

// Round 20
// 34.987 us; speedup vs baseline: 1.2540x; 1.2268x over previous
//
#include <hip/hip_runtime.h>

#define DTF (1.0f/120.0f)

constexpr int Bn = 2048, Tn = 2048, NS = Tn - 1, ZF = Tn * 3;
constexpr int NCH = 32, LCH = 64;     // 32*64 = 2048 >= 2047
constexpr int SPAN = 144;             // warm-up 81 after alignment
constexpr int BT = 64;                // one wave per block
constexpr int GX = Bn / BT;           // 32 trajectory groups
constexpr int NBLK = GX * NCH;        // 1024 blocks = 4 per CU (LDS-capped)
constexpr int RING = 6;               // LDS ring slots
constexpr int FR_F = 24;              // floats per row per frame (8 steps)
constexpr int SLOT_F = BT * FR_F;     // 1536 floats = 6144 B per slot

// ---- main: global_load_lds ring, swizzled rows, 4 blocks/CU ----
__global__ __launch_bounds__(BT, 2) void ekf_main(const float* __restrict__ params,
                                                  const float* __restrict__ meas,
                                                  double* __restrict__ part)
{
    __shared__ __align__(16) float lds[RING * SLOT_F];   // 36 KB
    const int tid = threadIdx.x;
    const int B = blockIdx.x;
    const int m = (B & 7) * 128 + (B >> 3);  // XCD-cluster: same group's chunks co-XCD
    const int g = m >> 5, c = m & 31;

    const float dt = DTF;
    const float fric = params[0];
    const float damping = params[1];
    const float a = 1.f - dt * damping;
    const float dfr = dt * fric;
    const float dt2 = dt * dt, a2 = a * a;
    const float qp = 2e-10f, qv = 3e-7f, qth = 1e-2f, qdth = 1e-1f;
    const float Rp = 2.5e-7f, Rt = 9.1e-3f;
    const char* __restrict__ ztb = (const char*)(meas + (size_t)(g * BT) * ZF);

    const int j0 = c * LCH;
    const int jend = min(j0 + LCH, NS);
    int jw = jend - SPAN;
    jw = (jw < 3) ? 0 : (jw - ((jw - 3) & 3));   // jw % 4 == 3, or 0 (exact head)
    const int A0f = (3 * jw) & ~3;               // frame-0 start float (aligned)
    const int d = 3 * jw + 3 - A0f;              // 4 (tail) or 3 (head)
    const int r0 = j0 - jw, r1 = jend - jw;
    const bool head = (jw == 0);

    // per-lane source precompute: instr i writes LDS unit U=i*64+tid (flat);
    // LDS row rowL=U/6 holds GLOBAL row G=(rowL&15)*4+(rowL>>4)  [digit swap]
    int Gbase[6], u16[6];
    #pragma unroll
    for (int i = 0; i < 6; ++i) {
        int U = i * 64 + tid;
        int rowL = U / 6, u = U - rowL * 6;
        int G = (rowL & 15) * 4 + (rowL >> 4);
        Gbase[i] = G * (ZF * 4);
        u16[i] = u * 16;
    }
    // read side: lane t reads LDS row rho(t) -> gets global row t; 4-way banks
    const int rbase = ((tid & 3) * 16 + (tid >> 2)) * FR_F;

#define ISSUE(F) do { \
    int As4_ = (A0f + 24 * (F)) * 4; \
    float* dst_ = &lds[((F) % RING) * SLOT_F]; \
    _Pragma("unroll") \
    for (int i_ = 0; i_ < 6; ++i_) { \
        int inrow_ = min(As4_ + u16[i_], (ZF - 4) * 4); \
        __builtin_amdgcn_global_load_lds((const void*)(ztb + Gbase[i_] + inrow_), \
                                         (void*)(dst_ + i_ * 256), 16, 0, 0); \
    } } while (0)

    ISSUE(0); ISSUE(1); ISSUE(2); ISSUE(3); ISSUE(4);   // 30 loads in flight

    // converged gains (tail): 48-iter 2x2 Riccati under the prologue loads
    float ckx0, ckx1, ckt0, ckt1, cisx, cist, cdet;
    {
        float x00=0.01f, x01=0.f, x11=0.01f, t00=0.01f, t01=0.f, t11=0.01f;
        for (int t = 0; t < 48; ++t) {
            float Pp00 = fmaf(dt2, x11, fmaf(2.f*dt, x01, x00)) + qp;
            float Pp01 = a * fmaf(dt, x11, x01);
            float Pp11 = fmaf(a2, x11, qv);
            float Sx = Pp00 + Rp, isx = __builtin_amdgcn_rcpf(Sx);
            float kx0 = Pp00*isx, kx1 = Pp01*isx;
            x00 = Pp00-kx0*Pp00; x01 = Pp01-kx0*Pp01; x11 = Pp11-kx1*Pp01;
            float Tp00 = fmaf(dt2, t11, fmaf(2.f*dt, t01, t00)) + qth;
            float Tp01 = fmaf(dt, t11, t01);
            float Tp11 = t11 + qdth;
            float St = Tp00 + Rt, ist = __builtin_amdgcn_rcpf(St);
            float kt0 = Tp00*ist, kt1 = Tp01*ist;
            t00 = Tp00-kt0*Tp00; t01 = Tp01-kt0*Tp01; t11 = Tp11-kt1*Tp01;
            ckx0=kx0; ckx1=kx1; ckt0=kt0; ckt1=kt1; cisx=isx; cist=ist; cdet=Sx*Sx*St;
        }
    }

    asm volatile("s_waitcnt vmcnt(24)" ::: "memory");    // frame 0 arrived
    __builtin_amdgcn_sched_barrier(0);

    // init state from frame 0: z[jw] at offset (d-3), z[jw+1] at (d)
    const int ib = d - 3;
    float b0 = lds[rbase+ib], b1 = lds[rbase+ib+1], b2 = lds[rbase+ib+2];
    float b3 = lds[rbase+ib+3], b4 = lds[rbase+ib+4], b5 = lds[rbase+ib+5];
    float s0 = b0, s1 = b1, s4 = b2;
    float s2 = (b3-b0)/dt, s3 = (b4-b1)/dt, s5 = (b5-b2)/dt;

    float facc = 0.f, accP = 0.f, accT = 0.f;
    int nown = 0;
    float hx00=0.01f, hx01=0.f, hx11=0.01f, ht00=0.01f, ht01=0.f, ht11=0.01f;

    for (int s = 0;; ++s) {
        ISSUE(s + 5);                                     // into slot (s-1)%6 (consumed)
        asm volatile("s_waitcnt vmcnt(24)" ::: "memory"); // frames s, s+1 arrived
        __builtin_amdgcn_sched_barrier(0);
        const float* sA = &lds[(s % RING) * SLOT_F + rbase];
        const float* sB = &lds[((s + 1) % RING) * SLOT_F + rbase];
        float zv[24];
        if (!head) {                                      // d == 4: aligned b128 reads
            float4 v0 = *(const float4*)(sA + 4);
            float4 v1 = *(const float4*)(sA + 8);
            float4 v2 = *(const float4*)(sA + 12);
            float4 v3 = *(const float4*)(sA + 16);
            float4 v4 = *(const float4*)(sA + 20);
            float4 v5 = *(const float4*)(sB);
            zv[0]=v0.x; zv[1]=v0.y; zv[2]=v0.z; zv[3]=v0.w;
            zv[4]=v1.x; zv[5]=v1.y; zv[6]=v1.z; zv[7]=v1.w;
            zv[8]=v2.x; zv[9]=v2.y; zv[10]=v2.z; zv[11]=v2.w;
            zv[12]=v3.x; zv[13]=v3.y; zv[14]=v3.z; zv[15]=v3.w;
            zv[16]=v4.x; zv[17]=v4.y; zv[18]=v4.z; zv[19]=v4.w;
            zv[20]=v5.x; zv[21]=v5.y; zv[22]=v5.z; zv[23]=v5.w;
            #pragma unroll
            for (int ss = 0; ss < 8; ++ss) {
                float p0 = fmaf(dt, s2, s0), p1 = fmaf(dt, s3, s1), p4 = fmaf(dt, s5, s4);
                float p2 = fmaf(a, s2, -copysignf(dfr, s2));
                float p3 = fmaf(a, s3, -copysignf(dfr, s3));
                float y0 = zv[3*ss]-p0, y1 = zv[3*ss+1]-p1, y2 = zv[3*ss+2]-p4;
                s0 = fmaf(ckx0, y0, p0); s1 = fmaf(ckx0, y1, p1);
                s2 = fmaf(ckx1, y0, p2); s3 = fmaf(ckx1, y1, p3);
                s4 = fmaf(ckt0, y2, p4); s5 = fmaf(ckt1, y2, s5);
                int r = 8*s + ss;
                if (r >= r0 && r < r1) {
                    accP = fmaf(y0, y0, fmaf(y1, y1, accP));
                    accT = fmaf(y2, y2, accT);
                    ++nown;
                }
            }
        } else {                                          // head: d == 3, exact Riccati
            #pragma unroll
            for (int k = 0; k < 21; ++k) zv[k] = sA[3 + k];
            zv[21] = sB[0]; zv[22] = sB[1]; zv[23] = sB[2];
            #pragma unroll
            for (int ss = 0; ss < 8; ++ss) {
                float Pp00 = fmaf(dt2, hx11, fmaf(2.f*dt, hx01, hx00)) + qp;
                float Pp01 = a * fmaf(dt, hx11, hx01);
                float Pp11 = fmaf(a2, hx11, qv);
                float Sx = Pp00 + Rp, isx = __builtin_amdgcn_rcpf(Sx);
                float kx0 = Pp00*isx, kx1 = Pp01*isx;
                hx00 = Pp00-kx0*Pp00; hx01 = Pp01-kx0*Pp01; hx11 = Pp11-kx1*Pp01;
                float Tp00 = fmaf(dt2, ht11, fmaf(2.f*dt, ht01, ht00)) + qth;
                float Tp01 = fmaf(dt, ht11, ht01);
                float Tp11 = ht11 + qdth;
                float St = Tp00 + Rt, ist = __builtin_amdgcn_rcpf(St);
                float kt0 = Tp00*ist, kt1 = Tp01*ist;
                ht00 = Tp00-kt0*Tp00; ht01 = Tp01-kt0*Tp01; ht11 = Tp11-kt1*Tp01;
                float p0 = fmaf(dt, s2, s0), p1 = fmaf(dt, s3, s1), p4 = fmaf(dt, s5, s4);
                float p2 = fmaf(a, s2, -copysignf(dfr, s2));
                float p3 = fmaf(a, s3, -copysignf(dfr, s3));
                float y0 = zv[3*ss]-p0, y1 = zv[3*ss+1]-p1, y2 = zv[3*ss+2]-p4;
                s0 = fmaf(kx0, y0, p0); s1 = fmaf(kx0, y1, p1);
                s2 = fmaf(kx1, y0, p2); s3 = fmaf(kx1, y1, p3);
                s4 = fmaf(kt0, y2, p4); s5 = fmaf(kt1, y2, s5);
                int r = 8*s + ss;
                if (r >= r0 && r < r1)
                    facc += Sx*Sx*St + isx*fmaf(y0, y0, y1*y1) + ist*y2*y2;
            }
        }
        if (8 * (s + 1) >= r1) break;
    }
    asm volatile("s_waitcnt vmcnt(0)" ::: "memory");      // drain before exit
#undef ISSUE

    if (!head) facc = (float)nown * cdet + cisx * accP + cist * accT;

    double acc = (double)facc;
    for (int off = 32; off; off >>= 1) acc += __shfl_down(acc, off);
    if (tid == 0) part[m] = acc;
}

// ---- finalize: reduce 1024 partials ----
__global__ void finalize_kernel(const double* __restrict__ part, float* __restrict__ out)
{
    const int tid = threadIdx.x;               // 1024 threads
    double v = part[tid];
    for (int off = 32; off; off >>= 1) v += __shfl_down(v, off);
    __shared__ double wp[16];
    if ((tid & 63) == 0) wp[tid >> 6] = v;
    __syncthreads();
    if (tid == 0) {
        double t = 0.0;
        #pragma unroll
        for (int i = 0; i < 16; ++i) t += wp[i];
        out[0] = (float)(t / ((double)Bn * (double)NS));
    }
}

extern "C" void kernel_launch(void* const* d_in, const int* in_sizes, int n_in,
                              void* d_out, int out_size, void* d_ws, size_t ws_size,
                              hipStream_t stream)
{
    const float* params = (const float*)d_in[0];
    const float* meas = (const float*)d_in[1];
    double* part = (double*)d_ws;
    float* out = (float*)d_out;

    hipLaunchKernelGGL(ekf_main, dim3(NBLK), dim3(BT), 0, stream, params, meas, part);
    hipLaunchKernelGGL(finalize_kernel, dim3(1), dim3(1024), 0, stream, part, out);
}

// Round 21
// 33.053 us; speedup vs baseline: 1.3274x; 1.0585x over previous
//
#include <hip/hip_runtime.h>

#define DTF (1.0f/120.0f)

constexpr int Bn = 2048, Tn = 2048, NS = Tn - 1, ZF = Tn * 3;
constexpr int NCH = 32, LCH = 64;     // 32*64 = 2048 >= 2047
constexpr int SPAN = 144;             // warm-up 81 after alignment
constexpr int BT = 64;                // one wave per block
constexpr int GX = Bn / BT;           // 32 trajectory groups
constexpr int NBLK = GX * NCH;        // 1024 blocks
constexpr int RING = 4;               // LDS ring slots (24 KB -> 6 blocks/CU)
constexpr int FR_F = 24;              // floats per row per frame (8 steps)
constexpr int SLOT_F = BT * FR_F;     // 1536 floats = 6144 B per slot

// ---- main: global_load_lds ring-4, swizzled rows, 6 blocks/CU ----
__global__ __launch_bounds__(BT, 2) void ekf_main(const float* __restrict__ params,
                                                  const float* __restrict__ meas,
                                                  double* __restrict__ part)
{
    __shared__ __align__(16) float lds[RING * SLOT_F];   // 24 KB
    const int tid = threadIdx.x;
    const int B = blockIdx.x;
    const int m = (B & 7) * 128 + (B >> 3);  // XCD-cluster: same group's chunks co-XCD
    const int g = m >> 5, c = m & 31;

    const float dt = DTF;
    const float fric = params[0];
    const float damping = params[1];
    const float a = 1.f - dt * damping;
    const float dfr = dt * fric;
    const float dt2 = dt * dt, a2 = a * a;
    const float qp = 2e-10f, qv = 3e-7f, qth = 1e-2f, qdth = 1e-1f;
    const float Rp = 2.5e-7f, Rt = 9.1e-3f;
    const char* __restrict__ ztb = (const char*)(meas + (size_t)(g * BT) * ZF);

    const int j0 = c * LCH;
    const int jend = min(j0 + LCH, NS);
    int jw = jend - SPAN;
    jw = (jw < 3) ? 0 : (jw - ((jw - 3) & 3));   // jw % 4 == 3, or 0 (exact head)
    const int A0f = (3 * jw) & ~3;               // frame-0 start float (aligned)
    const int d = 3 * jw + 3 - A0f;              // 4 (tail) or 3 (head)
    const int r0 = j0 - jw, r1 = jend - jw;
    const bool head = (jw == 0);

    // per-lane source precompute: instr i writes LDS unit U=i*64+tid (flat);
    // LDS row rowL=U/6 holds GLOBAL row G=(rowL&15)*4+(rowL>>4)  [digit swap]
    int Gbase[6], u16[6];
    #pragma unroll
    for (int i = 0; i < 6; ++i) {
        int U = i * 64 + tid;
        int rowL = U / 6, u = U - rowL * 6;
        int G = (rowL & 15) * 4 + (rowL >> 4);
        Gbase[i] = G * (ZF * 4);
        u16[i] = u * 16;
    }
    // read side: lane t reads LDS row rho(t) -> gets global row t; 4-way banks
    const int rbase = ((tid & 3) * 16 + (tid >> 2)) * FR_F;

#define ISSUE(F) do { \
    int As4_ = (A0f + 24 * (F)) * 4; \
    float* dst_ = &lds[((F) % RING) * SLOT_F]; \
    _Pragma("unroll") \
    for (int i_ = 0; i_ < 6; ++i_) { \
        int inrow_ = min(As4_ + u16[i_], (ZF - 4) * 4); \
        __builtin_amdgcn_global_load_lds((const void*)(ztb + Gbase[i_] + inrow_), \
                                         (void*)(dst_ + i_ * 256), 16, 0, 0); \
    } } while (0)

    ISSUE(0); ISSUE(1); ISSUE(2);                       // 18 loads in flight

    // converged gains (tail): 48-iter 2x2 Riccati under the prologue loads
    float ckx0, ckx1, ckt0, ckt1, cisx, cist, cdet;
    {
        float x00=0.01f, x01=0.f, x11=0.01f, t00=0.01f, t01=0.f, t11=0.01f;
        for (int t = 0; t < 48; ++t) {
            float Pp00 = fmaf(dt2, x11, fmaf(2.f*dt, x01, x00)) + qp;
            float Pp01 = a * fmaf(dt, x11, x01);
            float Pp11 = fmaf(a2, x11, qv);
            float Sx = Pp00 + Rp, isx = __builtin_amdgcn_rcpf(Sx);
            float kx0 = Pp00*isx, kx1 = Pp01*isx;
            x00 = Pp00-kx0*Pp00; x01 = Pp01-kx0*Pp01; x11 = Pp11-kx1*Pp01;
            float Tp00 = fmaf(dt2, t11, fmaf(2.f*dt, t01, t00)) + qth;
            float Tp01 = fmaf(dt, t11, t01);
            float Tp11 = t11 + qdth;
            float St = Tp00 + Rt, ist = __builtin_amdgcn_rcpf(St);
            float kt0 = Tp00*ist, kt1 = Tp01*ist;
            t00 = Tp00-kt0*Tp00; t01 = Tp01-kt0*Tp01; t11 = Tp11-kt1*Tp01;
            ckx0=kx0; ckx1=kx1; ckt0=kt0; ckt1=kt1; cisx=isx; cist=ist; cdet=Sx*Sx*St;
        }
    }

    asm volatile("s_waitcnt vmcnt(12)" ::: "memory");    // frame 0 arrived
    __builtin_amdgcn_sched_barrier(0);

    // init state from frame 0: z[jw] at offset (d-3), z[jw+1] at (d)
    const int ib = d - 3;
    float b0 = lds[rbase+ib], b1 = lds[rbase+ib+1], b2 = lds[rbase+ib+2];
    float b3 = lds[rbase+ib+3], b4 = lds[rbase+ib+4], b5 = lds[rbase+ib+5];
    float s0 = b0, s1 = b1, s4 = b2;
    float s2 = (b3-b0)/dt, s3 = (b4-b1)/dt, s5 = (b5-b2)/dt;

    float facc = 0.f, accP = 0.f, accT = 0.f;
    int nown = 0;
    float hx00=0.01f, hx01=0.f, hx11=0.01f, ht00=0.01f, ht01=0.f, ht11=0.01f;

    for (int s = 0;; ++s) {
        ISSUE(s + 3);                                     // into slot (s-1)%4 (consumed)
        asm volatile("s_waitcnt vmcnt(12)" ::: "memory"); // frames s, s+1 arrived
        __builtin_amdgcn_sched_barrier(0);
        const float* sA = &lds[(s % RING) * SLOT_F + rbase];
        const float* sB = &lds[((s + 1) % RING) * SLOT_F + rbase];
        float zv[24];
        if (!head) {                                      // d == 4: aligned b128 reads
            float4 v0 = *(const float4*)(sA + 4);
            float4 v1 = *(const float4*)(sA + 8);
            float4 v2 = *(const float4*)(sA + 12);
            float4 v3 = *(const float4*)(sA + 16);
            float4 v4 = *(const float4*)(sA + 20);
            float4 v5 = *(const float4*)(sB);
            zv[0]=v0.x; zv[1]=v0.y; zv[2]=v0.z; zv[3]=v0.w;
            zv[4]=v1.x; zv[5]=v1.y; zv[6]=v1.z; zv[7]=v1.w;
            zv[8]=v2.x; zv[9]=v2.y; zv[10]=v2.z; zv[11]=v2.w;
            zv[12]=v3.x; zv[13]=v3.y; zv[14]=v3.z; zv[15]=v3.w;
            zv[16]=v4.x; zv[17]=v4.y; zv[18]=v4.z; zv[19]=v4.w;
            zv[20]=v5.x; zv[21]=v5.y; zv[22]=v5.z; zv[23]=v5.w;
            #pragma unroll
            for (int ss = 0; ss < 8; ++ss) {
                float p0 = fmaf(dt, s2, s0), p1 = fmaf(dt, s3, s1), p4 = fmaf(dt, s5, s4);
                float p2 = fmaf(a, s2, -copysignf(dfr, s2));
                float p3 = fmaf(a, s3, -copysignf(dfr, s3));
                float y0 = zv[3*ss]-p0, y1 = zv[3*ss+1]-p1, y2 = zv[3*ss+2]-p4;
                s0 = fmaf(ckx0, y0, p0); s1 = fmaf(ckx0, y1, p1);
                s2 = fmaf(ckx1, y0, p2); s3 = fmaf(ckx1, y1, p3);
                s4 = fmaf(ckt0, y2, p4); s5 = fmaf(ckt1, y2, s5);
                int r = 8*s + ss;
                if (r >= r0 && r < r1) {
                    accP = fmaf(y0, y0, fmaf(y1, y1, accP));
                    accT = fmaf(y2, y2, accT);
                    ++nown;
                }
            }
        } else {                                          // head: d == 3, exact Riccati
            #pragma unroll
            for (int k = 0; k < 21; ++k) zv[k] = sA[3 + k];
            zv[21] = sB[0]; zv[22] = sB[1]; zv[23] = sB[2];
            #pragma unroll
            for (int ss = 0; ss < 8; ++ss) {
                float Pp00 = fmaf(dt2, hx11, fmaf(2.f*dt, hx01, hx00)) + qp;
                float Pp01 = a * fmaf(dt, hx11, hx01);
                float Pp11 = fmaf(a2, hx11, qv);
                float Sx = Pp00 + Rp, isx = __builtin_amdgcn_rcpf(Sx);
                float kx0 = Pp00*isx, kx1 = Pp01*isx;
                hx00 = Pp00-kx0*Pp00; hx01 = Pp01-kx0*Pp01; hx11 = Pp11-kx1*Pp01;
                float Tp00 = fmaf(dt2, ht11, fmaf(2.f*dt, ht01, ht00)) + qth;
                float Tp01 = fmaf(dt, ht11, ht01);
                float Tp11 = ht11 + qdth;
                float St = Tp00 + Rt, ist = __builtin_amdgcn_rcpf(St);
                float kt0 = Tp00*ist, kt1 = Tp01*ist;
                ht00 = Tp00-kt0*Tp00; ht01 = Tp01-kt0*Tp01; ht11 = Tp11-kt1*Tp01;
                float p0 = fmaf(dt, s2, s0), p1 = fmaf(dt, s3, s1), p4 = fmaf(dt, s5, s4);
                float p2 = fmaf(a, s2, -copysignf(dfr, s2));
                float p3 = fmaf(a, s3, -copysignf(dfr, s3));
                float y0 = zv[3*ss]-p0, y1 = zv[3*ss+1]-p1, y2 = zv[3*ss+2]-p4;
                s0 = fmaf(kx0, y0, p0); s1 = fmaf(kx0, y1, p1);
                s2 = fmaf(kx1, y0, p2); s3 = fmaf(kx1, y1, p3);
                s4 = fmaf(kt0, y2, p4); s5 = fmaf(kt1, y2, s5);
                int r = 8*s + ss;
                if (r >= r0 && r < r1)
                    facc += Sx*Sx*St + isx*fmaf(y0, y0, y1*y1) + ist*y2*y2;
            }
        }
        if (8 * (s + 1) >= r1) break;
    }
    asm volatile("s_waitcnt vmcnt(0)" ::: "memory");      // drain before exit
#undef ISSUE

    if (!head) facc = (float)nown * cdet + cisx * accP + cist * accT;

    double acc = (double)facc;
    for (int off = 32; off; off >>= 1) acc += __shfl_down(acc, off);
    if (tid == 0) part[m] = acc;
}

// ---- finalize: reduce 1024 partials ----
__global__ void finalize_kernel(const double* __restrict__ part, float* __restrict__ out)
{
    const int tid = threadIdx.x;               // 1024 threads
    double v = part[tid];
    for (int off = 32; off; off >>= 1) v += __shfl_down(v, off);
    __shared__ double wp[16];
    if ((tid & 63) == 0) wp[tid >> 6] = v;
    __syncthreads();
    if (tid == 0) {
        double t = 0.0;
        #pragma unroll
        for (int i = 0; i < 16; ++i) t += wp[i];
        out[0] = (float)(t / ((double)Bn * (double)NS));
    }
}

extern "C" void kernel_launch(void* const* d_in, const int* in_sizes, int n_in,
                              void* d_out, int out_size, void* d_ws, size_t ws_size,
                              hipStream_t stream)
{
    const float* params = (const float*)d_in[0];
    const float* meas = (const float*)d_in[1];
    double* part = (double*)d_ws;
    float* out = (float*)d_out;

    hipLaunchKernelGGL(ekf_main, dim3(NBLK), dim3(BT), 0, stream, params, meas, part);
    hipLaunchKernelGGL(finalize_kernel, dim3(1), dim3(1024), 0, stream, part, out);
}